// Round 4
// baseline (914.626 us; speedup 1.0000x reference)
//
#include <hip/hip_runtime.h>
#include <hip/hip_bf16.h>

typedef __bf16 bf16_t;
typedef bf16_t bf16x4 __attribute__((ext_vector_type(4)));
typedef bf16_t bf16x8 __attribute__((ext_vector_type(8)));
typedef float f32x4 __attribute__((ext_vector_type(4)));

static constexpr int N_NODES = 50000;
static constexpr int N_EDGES = 1600000;
static constexpr int FIN = 1280;
static constexpr int HD = 128;
static constexpr int NG = 64;
// 0.5/sqrt(pi)/sqrt(128)
static constexpr float TP_NORM_F = 0.0249338908f;

// ---- fused transpose+scale+cast of the three weight matrices
// lin_w [1280x128]->WtL[128x1280]; tp_w1,tp_w2 [128x128]->Wt1,Wt2[128x128]*TP_NORM
__global__ __launch_bounds__(256) void k_transpose_all(const float* __restrict__ lin_w,
                                                       const float* __restrict__ tp_w1,
                                                       const float* __restrict__ tp_w2,
                                                       bf16_t* __restrict__ WtL,
                                                       bf16_t* __restrict__ Wt1,
                                                       bf16_t* __restrict__ Wt2) {
  int idx = blockIdx.x * 256 + threadIdx.x;
  const int A1 = FIN * HD;        // 163840
  const int A2 = A1 + HD * HD;    // +16384
  const int A3 = A2 + HD * HD;
  if (idx < A1) {
    int k = idx >> 7, n = idx & 127;
    WtL[n * FIN + k] = (bf16_t)lin_w[idx];
  } else if (idx < A2) {
    int j = idx - A1;
    int k = j >> 7, n = j & 127;
    Wt1[n * HD + k] = (bf16_t)(tp_w1[j] * TP_NORM_F);
  } else if (idx < A3) {
    int j = idx - A2;
    int k = j >> 7, n = j & 127;
    Wt2[n * HD + k] = (bf16_t)(tp_w2[j] * TP_NORM_F);
  }
}

// ---- LDS-free, barrier-free streaming GEMM: C[M x 128] = act(A[M x K] @ Bt^T + bias)
// One wave owns 16 rows and all 128 cols (8 MFMA col-tiles). A-fragment loaded
// directly from global (layout A[m=l15][k=quad*8+j]); B-fragments from bf16 Bt
// (L2-resident). Zero __syncthreads; latency hidden purely by occupancy.
template <typename AT>
__global__ __launch_bounds__(256) void k_gemm_stream(const AT* __restrict__ A,
                                                     const bf16_t* __restrict__ Bt,
                                                     const float* __restrict__ bias,
                                                     bf16_t* __restrict__ C,
                                                     int M, int K, int doRelu) {
  const int w = (blockIdx.x * 256 + threadIdx.x) >> 6;  // global wave id
  if (w * 16 >= M) return;
  const int lane = threadIdx.x & 63;
  const int l15 = lane & 15;
  const int quad = lane >> 4;
  const int rowA = w * 16 + l15;

  f32x4 acc[8];
#pragma unroll
  for (int t = 0; t < 8; ++t) {
    f32x4 z = {0.f, 0.f, 0.f, 0.f};
    acc[t] = z;
  }

  const AT* ap = A + (size_t)rowA * K + quad * 8;
  const bf16_t* bp = Bt + (size_t)l15 * K + quad * 8;

#pragma unroll 2
  for (int k0 = 0; k0 < K; k0 += 32) {
    bf16x8 af;
    if constexpr (sizeof(AT) == 4) {
      f32x4 a0 = *(const f32x4*)(ap + k0);
      f32x4 a1 = *(const f32x4*)(ap + k0 + 4);
#pragma unroll
      for (int j = 0; j < 4; ++j) { af[j] = (bf16_t)a0[j]; af[j + 4] = (bf16_t)a1[j]; }
    } else {
      af = *(const bf16x8*)(ap + k0);
    }
#pragma unroll
    for (int t = 0; t < 8; ++t) {
      bf16x8 bf = *(const bf16x8*)(bp + (size_t)t * 16 * K + k0);
      acc[t] = __builtin_amdgcn_mfma_f32_16x16x32_bf16(af, bf, acc[t], 0, 0, 0);
    }
  }

  // epilogue: C/D layout col=lane&15, row=quad*4+reg (m89-verified)
#pragma unroll
  for (int t = 0; t < 8; ++t) {
    int col = t * 16 + l15;
    float bv = bias ? bias[col] : 0.f;
#pragma unroll
    for (int r = 0; r < 4; ++r) {
      int gr = w * 16 + quad * 4 + r;
      float v = acc[t][r] + bv;
      if (doRelu) v = fmaxf(v, 0.f);
      C[(size_t)gr * HD + col] = (bf16_t)v;
    }
  }
}

// ---- CSR build: pass1 computes per-edge slot via one atomic (also yields counts)
__global__ __launch_bounds__(256) void k_pos(const int* __restrict__ dst, int* __restrict__ cnt,
                                             int* __restrict__ pos, int E) {
  int e = blockIdx.x * 256 + threadIdx.x;
  if (e < E) pos[e] = atomicAdd(&cnt[dst[e]], 1);
}

// hierarchical scan: (1) per-block sums, (2) scan block sums, (3) add-back
__global__ __launch_bounds__(256) void k_scan1(const int* __restrict__ cnt, int* __restrict__ bsum, int n) {
  __shared__ int s[256];
  int t = threadIdx.x;
  int i = blockIdx.x * 256 + t;
  s[t] = (i < n) ? cnt[i] : 0;
  __syncthreads();
  for (int d = 128; d > 0; d >>= 1) {
    if (t < d) s[t] += s[t + d];
    __syncthreads();
  }
  if (t == 0) bsum[blockIdx.x] = s[0];
}

__global__ __launch_bounds__(256) void k_scan2(int* __restrict__ bsum, int nb) {
  __shared__ int s[256];
  int t = threadIdx.x;
  int v = (t < nb) ? bsum[t] : 0;
  s[t] = v;
  __syncthreads();
  for (int d = 1; d < 256; d <<= 1) {
    int x = (t >= d) ? s[t - d] : 0;
    __syncthreads();
    s[t] += x;
    __syncthreads();
  }
  if (t < nb) bsum[t] = s[t] - v;  // exclusive
  if (t == 255) bsum[nb] = s[255]; // total
}

__global__ __launch_bounds__(256) void k_scan3(const int* __restrict__ cnt, const int* __restrict__ bsum,
                                               int* __restrict__ off, int n) {
  __shared__ int s[256];
  int t = threadIdx.x;
  int i = blockIdx.x * 256 + t;
  int v = (i < n) ? cnt[i] : 0;
  s[t] = v;
  __syncthreads();
  for (int d = 1; d < 256; d <<= 1) {
    int x = (t >= d) ? s[t - d] : 0;
    __syncthreads();
    s[t] += x;
    __syncthreads();
  }
  if (i < n) off[i] = bsum[blockIdx.x] + s[t] - v;
  if (i == n - 1) off[n] = bsum[blockIdx.x] + s[t];
}

__global__ __launch_bounds__(256) void k_fill(const int* __restrict__ src, const int* __restrict__ dst,
                                              const int* __restrict__ off, const int* __restrict__ pos,
                                              int* __restrict__ ssrc, int E) {
  int e = blockIdx.x * 256 + threadIdx.x;
  if (e >= E) return;
  ssrc[off[dst[e]] + pos[e]] = src[e];
}

// ---- CSR mean-aggregate, wave-per-node: 4 lane-groups x 16 lanes.
// Group g handles edges i+g; lane&15 holds feature slice of 8 bf16 (16B loads).
// Main loop keeps 4 gathers in flight per lane.
__global__ __launch_bounds__(256) void k_aggregate(const bf16_t* __restrict__ h,
                                                   const int* __restrict__ ssrc,
                                                   const int* __restrict__ off,
                                                   bf16_t* __restrict__ agg, int n) {
  int node = blockIdx.x * 4 + (threadIdx.x >> 6);
  if (node >= n) return;
  int lane = threadIdx.x & 63;
  int g = lane >> 4;
  int fl = lane & 15;
  int b = off[node], e = off[node + 1];
  float acc[8];
#pragma unroll
  for (int j = 0; j < 8; ++j) acc[j] = 0.f;
  const bf16_t* hp = h + fl * 8;
  int i = b;
  for (; i + 16 <= e; i += 16) {
    int s0 = ssrc[i + g];
    int s1 = ssrc[i + 4 + g];
    int s2 = ssrc[i + 8 + g];
    int s3 = ssrc[i + 12 + g];
    bf16x8 v0 = *(const bf16x8*)(hp + (size_t)s0 * HD);
    bf16x8 v1 = *(const bf16x8*)(hp + (size_t)s1 * HD);
    bf16x8 v2 = *(const bf16x8*)(hp + (size_t)s2 * HD);
    bf16x8 v3 = *(const bf16x8*)(hp + (size_t)s3 * HD);
#pragma unroll
    for (int j = 0; j < 8; ++j)
      acc[j] += ((float)v0[j] + (float)v1[j]) + ((float)v2[j] + (float)v3[j]);
  }
  if (i + 8 <= e) {
    int s0 = ssrc[i + g];
    int s1 = ssrc[i + 4 + g];
    bf16x8 v0 = *(const bf16x8*)(hp + (size_t)s0 * HD);
    bf16x8 v1 = *(const bf16x8*)(hp + (size_t)s1 * HD);
#pragma unroll
    for (int j = 0; j < 8; ++j) acc[j] += (float)v0[j] + (float)v1[j];
    i += 8;
  }
  if (i + 4 <= e) {
    int s0 = ssrc[i + g];
    bf16x8 v0 = *(const bf16x8*)(hp + (size_t)s0 * HD);
#pragma unroll
    for (int j = 0; j < 8; ++j) acc[j] += (float)v0[j];
    i += 4;
  }
  if (i + g < e) {
    int s0 = ssrc[i + g];
    bf16x8 v0 = *(const bf16x8*)(hp + (size_t)s0 * HD);
#pragma unroll
    for (int j = 0; j < 8; ++j) acc[j] += (float)v0[j];
  }
  // reduce across the 4 lane-groups (lanes with equal lane&15 hold same slice)
#pragma unroll
  for (int j = 0; j < 8; ++j) {
    acc[j] += __shfl_xor(acc[j], 16);
    acc[j] += __shfl_xor(acc[j], 32);
  }
  if (g == 0) {
    float inv = (e > b) ? 1.f / (float)(e - b) : 0.f;
    bf16x8 o;
#pragma unroll
    for (int j = 0; j < 8; ++j) o[j] = (bf16_t)(acc[j] * inv);
    *(bf16x8*)(agg + (size_t)node * HD + fl * 8) = o;
  }
}

// ---- pool: block-per-graph, binary-search boundaries in sorted batch,
// parallel mean over the graph's rows. Writes the MEAN directly (no atomics).
__global__ __launch_bounds__(256) void k_pool(const bf16_t* __restrict__ agg,
                                              const int* __restrict__ batch,
                                              float* __restrict__ p, int n) {
  __shared__ float s[256];
  int g = blockIdx.x;
  int t = threadIdx.x;
  // lower_bound(batch, g) and lower_bound(batch, g+1)
  int lo = 0, hi = n;
  while (lo < hi) { int m = (lo + hi) >> 1; if (batch[m] < g) lo = m + 1; else hi = m; }
  int lo2 = lo, hi2 = n;
  while (lo2 < hi2) { int m = (lo2 + hi2) >> 1; if (batch[m] < g + 1) lo2 = m + 1; else hi2 = m; }
  int count = lo2 - lo;
  int f = t & 127;
  int half = t >> 7;  // 0 or 1: split rows between thread-halves
  float acc = 0.f;
  for (int i = lo + half; i < lo2; i += 2)
    acc += (float)agg[(size_t)i * HD + f];
  s[t] = acc;
  __syncthreads();
  if (t < 128) {
    float v = s[t] + s[t + 128];
    float inv = (count > 0) ? 1.f / (float)count : 0.f;
    p[g * HD + t] = v * inv;
  }
}

// ---- head: z = p @ (w3*norm); out = mlp(z). One block per graph. p is already the mean.
__global__ __launch_bounds__(128) void k_head(const float* __restrict__ p,
                                              const float* __restrict__ w3,
                                              const float* __restrict__ c1w, const float* __restrict__ c1b,
                                              const float* __restrict__ c2w, const float* __restrict__ c2b,
                                              const float* __restrict__ c3w, const float* __restrict__ c3b,
                                              float* __restrict__ out) {
  __shared__ float sa[128], sb[128];
  int g = blockIdx.x, t = threadIdx.x;
  sa[t] = p[g * HD + t];
  __syncthreads();
  float z = 0.f;
  for (int k = 0; k < HD; ++k) z += sa[k] * w3[k * HD + t];
  z *= TP_NORM_F;
  out[128 + g * HD + t] = z;  // second output (z) region
  sb[t] = z;
  __syncthreads();
  float o1 = c1b[t];
  for (int k = 0; k < HD; ++k) o1 += sb[k] * c1w[k * HD + t];
  o1 = fmaxf(o1, 0.f);
  __syncthreads();
  sa[t] = o1;
  __syncthreads();
  float o2 = c2b[t];
  for (int k = 0; k < HD; ++k) o2 += sa[k] * c2w[k * HD + t];
  o2 = fmaxf(o2, 0.f);
  __syncthreads();
  sb[t] = o2;
  __syncthreads();
  if (t < 2) {
    float o = c3b[t];
    for (int k = 0; k < HD; ++k) o += sb[k] * c3w[k * 2 + t];
    out[g * 2 + t] = o;  // first output region
  }
}

extern "C" void kernel_launch(void* const* d_in, const int* in_sizes, int n_in,
                              void* d_out, int out_size, void* d_ws, size_t ws_size,
                              hipStream_t stream) {
  const float* x = (const float*)d_in[0];
  const int* eidx = (const int*)d_in[2];
  const int* src = eidx;
  const int* dst = eidx + N_EDGES;
  const int* batch = (const int*)d_in[3];
  const float* lin_w = (const float*)d_in[4];
  const float* lin_b = (const float*)d_in[5];
  const float* tp_w1 = (const float*)d_in[6];
  const float* tp_w2 = (const float*)d_in[7];
  const float* tp_w3 = (const float*)d_in[8];
  const float* c1w = (const float*)d_in[9];
  const float* c1b = (const float*)d_in[10];
  const float* c2w = (const float*)d_in[11];
  const float* c2b = (const float*)d_in[12];
  const float* c3w = (const float*)d_in[13];
  const float* c3b = (const float*)d_in[14];
  float* out = (float*)d_out;
  (void)in_sizes; (void)n_in; (void)out_size; (void)ws_size;

  uintptr_t wp = (uintptr_t)d_ws;
  auto alloc = [&](size_t bytes) -> void* {
    uintptr_t a = (wp + 255) & ~(uintptr_t)255;
    wp = a + bytes;
    return (void*)a;
  };
  bf16_t* WtL  = (bf16_t*)alloc(sizeof(bf16_t) * (size_t)HD * FIN);
  bf16_t* Wt1  = (bf16_t*)alloc(sizeof(bf16_t) * (size_t)HD * HD);
  bf16_t* Wt2  = (bf16_t*)alloc(sizeof(bf16_t) * (size_t)HD * HD);
  bf16_t* h    = (bf16_t*)alloc(sizeof(bf16_t) * (size_t)50048 * HD);
  bf16_t* agg  = (bf16_t*)alloc(sizeof(bf16_t) * (size_t)50048 * HD);
  int*    cnt  = (int*)alloc(sizeof(int) * N_NODES);
  int*    bsum = (int*)alloc(sizeof(int) * 256);
  int*    offs = (int*)alloc(sizeof(int) * (N_NODES + 1));
  int*    pos  = (int*)alloc(sizeof(int) * N_EDGES);
  int*    ssrc = (int*)alloc(sizeof(int) * N_EDGES);
  float*  pbuf = (float*)alloc(sizeof(float) * NG * HD);

  hipMemsetAsync(cnt, 0, sizeof(int) * N_NODES, stream);

  k_transpose_all<<<(FIN * HD + 2 * HD * HD + 255) / 256, 256, 0, stream>>>(
      lin_w, tp_w1, tp_w2, WtL, Wt1, Wt2);

  const int nScanBlocks = (N_NODES + 255) / 256;  // 196
  k_pos<<<(N_EDGES + 255) / 256, 256, 0, stream>>>(dst, cnt, pos, N_EDGES);
  k_scan1<<<nScanBlocks, 256, 0, stream>>>(cnt, bsum, N_NODES);
  k_scan2<<<1, 256, 0, stream>>>(bsum, nScanBlocks);
  k_scan3<<<nScanBlocks, 256, 0, stream>>>(cnt, bsum, offs, N_NODES);
  k_fill<<<(N_EDGES + 255) / 256, 256, 0, stream>>>(src, dst, offs, pos, ssrc, N_EDGES);

  const int nWaves = N_NODES / 16;               // 3125 (50000 % 16 == 0)
  const int gblocks = (nWaves + 3) / 4;          // 782
  const int ablocks = (N_NODES + 3) / 4;         // 12500

  // h0 = relu(x @ lin_w + b)
  k_gemm_stream<float><<<gblocks, 256, 0, stream>>>(x, WtL, lin_b, h, N_NODES, FIN, 1);

  // conv1: agg = mean_agg(h0[src]); h1 = relu(agg @ W1*norm)
  k_aggregate<<<ablocks, 256, 0, stream>>>(h, ssrc, offs, agg, N_NODES);
  k_gemm_stream<bf16_t><<<gblocks, 256, 0, stream>>>(agg, Wt1, nullptr, h, N_NODES, HD, 1);
  // conv2
  k_aggregate<<<ablocks, 256, 0, stream>>>(h, ssrc, offs, agg, N_NODES);
  k_gemm_stream<bf16_t><<<gblocks, 256, 0, stream>>>(agg, Wt2, nullptr, h, N_NODES, HD, 1);
  // conv3 aggregation only (W3 folded into head via linearity of segment-mean)
  k_aggregate<<<ablocks, 256, 0, stream>>>(h, ssrc, offs, agg, N_NODES);

  k_pool<<<NG, 256, 0, stream>>>(agg, batch, pbuf, N_NODES);
  k_head<<<NG, 128, 0, stream>>>(pbuf, tp_w3, c1w, c1b, c2w, c2b, c3w, c3b, out);
}

// Round 5
// 805.011 us; speedup vs baseline: 1.1362x; 1.1362x over previous
//
#include <hip/hip_runtime.h>
#include <hip/hip_bf16.h>

typedef __bf16 bf16_t;
typedef bf16_t bf16x4 __attribute__((ext_vector_type(4)));
typedef bf16_t bf16x8 __attribute__((ext_vector_type(8)));
typedef float f32x4 __attribute__((ext_vector_type(4)));

static constexpr int N_NODES = 50000;
static constexpr int N_EDGES = 1600000;
static constexpr int FIN = 1280;
static constexpr int HD = 128;
static constexpr int NG = 64;
// 0.5/sqrt(pi)/sqrt(128)
static constexpr float TP_NORM_F = 0.0249338908f;

// ---- fused transpose+scale+cast of the three weight matrices
__global__ __launch_bounds__(256) void k_transpose_all(const float* __restrict__ lin_w,
                                                       const float* __restrict__ tp_w1,
                                                       const float* __restrict__ tp_w2,
                                                       bf16_t* __restrict__ WtL,
                                                       bf16_t* __restrict__ Wt1,
                                                       bf16_t* __restrict__ Wt2) {
  int idx = blockIdx.x * 256 + threadIdx.x;
  const int A1 = FIN * HD;        // 163840
  const int A2 = A1 + HD * HD;    // +16384
  const int A3 = A2 + HD * HD;
  if (idx < A1) {
    int k = idx >> 7, n = idx & 127;
    WtL[n * FIN + k] = (bf16_t)lin_w[idx];
  } else if (idx < A2) {
    int j = idx - A1;
    int k = j >> 7, n = j & 127;
    Wt1[n * HD + k] = (bf16_t)(tp_w1[j] * TP_NORM_F);
  } else if (idx < A3) {
    int j = idx - A2;
    int k = j >> 7, n = j & 127;
    Wt2[n * HD + k] = (bf16_t)(tp_w2[j] * TP_NORM_F);
  }
}

// ---- MFMA GEMM: C[M x 128] = act(A[M x K] @ Bt^T + bias)
// 32x128 block tile, 4 waves x (32x32), BK=64, XOR-swizzled LDS.
// Explicit 2-stage pipeline: global->reg loads for tile k+1 issued BEFORE
// compute(k); reg->LDS stores AFTER compute(k); one barrier per K-step.
template <typename AT>
__global__ __launch_bounds__(256) void k_gemm32(const AT* __restrict__ A,
                                                const bf16_t* __restrict__ Bt,
                                                const float* __restrict__ bias,
                                                bf16_t* __restrict__ C,
                                                int M, int K, int doRelu) {
  __shared__ bf16_t As[2][32 * 64];
  __shared__ bf16_t Bs[2][128 * 64];
  const int t = threadIdx.x;
  const int wid = t >> 6;
  const int lane = t & 63;
  const int wn = wid * 32;
  const int l15 = lane & 15;
  const int quad = lane >> 4;
  const int rowBase = blockIdx.x * 32;

  f32x4 acc[2][2];
#pragma unroll
  for (int i = 0; i < 2; ++i)
#pragma unroll
    for (int j = 0; j < 2; ++j) {
      f32x4 z = {0.f, 0.f, 0.f, 0.f};
      acc[i][j] = z;
    }

  // staging registers
  float4 aregF[2];
  bf16x8 aregB;
  bf16x8 breg[4];

  auto loadA = [&](int k0) {
    if constexpr (sizeof(AT) == 4) {
#pragma unroll
      for (int i = 0; i < 2; ++i) {
        int idx = t + i * 256;
        int row = idx >> 4;   // 0..31
        int col4 = idx & 15;  // float4 units
        int gr = rowBase + row;
        aregF[i] = make_float4(0.f, 0.f, 0.f, 0.f);
        if (gr < M) aregF[i] = *(const float4*)(A + (size_t)gr * K + k0 + col4 * 4);
      }
    } else {
      int row = t >> 3;  // 0..31
      int c = t & 7;
      int gr = rowBase + row;
      bf16x8 v = {};
      if (gr < M) v = *(const bf16x8*)(A + (size_t)gr * K + k0 + c * 8);
      aregB = v;
    }
  };
  auto loadB = [&](int k0) {
#pragma unroll
    for (int i = 0; i < 4; ++i) {
      int idx = t + i * 256;
      int row = idx >> 3;  // 0..127
      int c = idx & 7;
      breg[i] = *(const bf16x8*)(Bt + (size_t)row * K + k0 + c * 8);
    }
  };
  auto storeA = [&](int buf) {
    if constexpr (sizeof(AT) == 4) {
#pragma unroll
      for (int i = 0; i < 2; ++i) {
        int idx = t + i * 256;
        int row = idx >> 4;
        int col4 = idx & 15;
        bf16x4 w;
        w[0] = (bf16_t)aregF[i].x; w[1] = (bf16_t)aregF[i].y;
        w[2] = (bf16_t)aregF[i].z; w[3] = (bf16_t)aregF[i].w;
        int c = col4 >> 1;
        int off = row * 64 + ((c ^ (row & 7)) << 3) + ((col4 & 1) << 2);
        *(bf16x4*)&As[buf][off] = w;
      }
    } else {
      int row = t >> 3;
      int c = t & 7;
      int off = row * 64 + ((c ^ (row & 7)) << 3);
      *(bf16x8*)&As[buf][off] = aregB;
    }
  };
  auto storeB = [&](int buf) {
#pragma unroll
    for (int i = 0; i < 4; ++i) {
      int idx = t + i * 256;
      int row = idx >> 3;
      int c = idx & 7;
      int off = row * 64 + ((c ^ (row & 7)) << 3);
      *(bf16x8*)&Bs[buf][off] = breg[i];
    }
  };
  auto compute = [&](int buf) {
#pragma unroll
    for (int kk = 0; kk < 2; ++kk) {
      bf16x8 af[2], bfr[2];
      int k8 = kk * 4 + quad;
#pragma unroll
      for (int mi = 0; mi < 2; ++mi) {
        int row = mi * 16 + l15;
        af[mi] = *(const bf16x8*)&As[buf][row * 64 + ((k8 ^ (row & 7)) << 3)];
      }
#pragma unroll
      for (int ni = 0; ni < 2; ++ni) {
        int row = wn + ni * 16 + l15;
        bfr[ni] = *(const bf16x8*)&Bs[buf][row * 64 + ((k8 ^ (row & 7)) << 3)];
      }
#pragma unroll
      for (int mi = 0; mi < 2; ++mi)
#pragma unroll
        for (int ni = 0; ni < 2; ++ni)
          acc[mi][ni] = __builtin_amdgcn_mfma_f32_16x16x32_bf16(af[mi], bfr[ni], acc[mi][ni], 0, 0, 0);
    }
  };

  const int nIter = K >> 6;
  loadA(0); loadB(0);
  storeA(0); storeB(0);
  __syncthreads();
  for (int it = 0; it < nIter; ++it) {
    int cur = it & 1;
    if (it + 1 < nIter) { loadA((it + 1) << 6); loadB((it + 1) << 6); }
    compute(cur);
    if (it + 1 < nIter) { storeA(cur ^ 1); storeB(cur ^ 1); }
    __syncthreads();
  }

  // epilogue: C/D layout col=lane&15, row=quad*4+reg (m89-verified)
#pragma unroll
  for (int mi = 0; mi < 2; ++mi) {
#pragma unroll
    for (int ni = 0; ni < 2; ++ni) {
      int col = wn + ni * 16 + l15;
      float bv = bias ? bias[col] : 0.f;
#pragma unroll
      for (int r = 0; r < 4; ++r) {
        int row = mi * 16 + quad * 4 + r;
        int gr = rowBase + row;
        if (gr < M) {
          float v = acc[mi][ni][r] + bv;
          if (doRelu) v = fmaxf(v, 0.f);
          C[(size_t)gr * HD + col] = (bf16_t)v;
        }
      }
    }
  }
}

// ---- CSR build: pass1 computes per-edge slot via one atomic (also yields counts)
__global__ __launch_bounds__(256) void k_pos(const int* __restrict__ dst, int* __restrict__ cnt,
                                             int* __restrict__ pos, int E) {
  int e = blockIdx.x * 256 + threadIdx.x;
  if (e < E) pos[e] = atomicAdd(&cnt[dst[e]], 1);
}

// hierarchical scan
__global__ __launch_bounds__(256) void k_scan1(const int* __restrict__ cnt, int* __restrict__ bsum, int n) {
  __shared__ int s[256];
  int t = threadIdx.x;
  int i = blockIdx.x * 256 + t;
  s[t] = (i < n) ? cnt[i] : 0;
  __syncthreads();
  for (int d = 128; d > 0; d >>= 1) {
    if (t < d) s[t] += s[t + d];
    __syncthreads();
  }
  if (t == 0) bsum[blockIdx.x] = s[0];
}

__global__ __launch_bounds__(256) void k_scan2(int* __restrict__ bsum, int nb) {
  __shared__ int s[256];
  int t = threadIdx.x;
  int v = (t < nb) ? bsum[t] : 0;
  s[t] = v;
  __syncthreads();
  for (int d = 1; d < 256; d <<= 1) {
    int x = (t >= d) ? s[t - d] : 0;
    __syncthreads();
    s[t] += x;
    __syncthreads();
  }
  if (t < nb) bsum[t] = s[t] - v;  // exclusive
  if (t == 255) bsum[nb] = s[255]; // total
}

__global__ __launch_bounds__(256) void k_scan3(const int* __restrict__ cnt, const int* __restrict__ bsum,
                                               int* __restrict__ off, int n) {
  __shared__ int s[256];
  int t = threadIdx.x;
  int i = blockIdx.x * 256 + t;
  int v = (i < n) ? cnt[i] : 0;
  s[t] = v;
  __syncthreads();
  for (int d = 1; d < 256; d <<= 1) {
    int x = (t >= d) ? s[t - d] : 0;
    __syncthreads();
    s[t] += x;
    __syncthreads();
  }
  if (i < n) off[i] = bsum[blockIdx.x] + s[t] - v;
  if (i == n - 1) off[n] = bsum[blockIdx.x] + s[t];
}

__global__ __launch_bounds__(256) void k_fill(const int* __restrict__ src, const int* __restrict__ dst,
                                              const int* __restrict__ off, const int* __restrict__ pos,
                                              int* __restrict__ ssrc, int E) {
  int e = blockIdx.x * 256 + threadIdx.x;
  if (e >= E) return;
  ssrc[off[dst[e]] + pos[e]] = src[e];
}

// ---- CSR mean-aggregate, wave-per-node: 4 lane-groups x 16 lanes.
__global__ __launch_bounds__(256) void k_aggregate(const bf16_t* __restrict__ h,
                                                   const int* __restrict__ ssrc,
                                                   const int* __restrict__ off,
                                                   bf16_t* __restrict__ agg, int n) {
  int node = blockIdx.x * 4 + (threadIdx.x >> 6);
  if (node >= n) return;
  int lane = threadIdx.x & 63;
  int g = lane >> 4;
  int fl = lane & 15;
  int b = off[node], e = off[node + 1];
  float acc[8];
#pragma unroll
  for (int j = 0; j < 8; ++j) acc[j] = 0.f;
  const bf16_t* hp = h + fl * 8;
  int i = b;
  for (; i + 16 <= e; i += 16) {
    int s0 = ssrc[i + g];
    int s1 = ssrc[i + 4 + g];
    int s2 = ssrc[i + 8 + g];
    int s3 = ssrc[i + 12 + g];
    bf16x8 v0 = *(const bf16x8*)(hp + (size_t)s0 * HD);
    bf16x8 v1 = *(const bf16x8*)(hp + (size_t)s1 * HD);
    bf16x8 v2 = *(const bf16x8*)(hp + (size_t)s2 * HD);
    bf16x8 v3 = *(const bf16x8*)(hp + (size_t)s3 * HD);
#pragma unroll
    for (int j = 0; j < 8; ++j)
      acc[j] += ((float)v0[j] + (float)v1[j]) + ((float)v2[j] + (float)v3[j]);
  }
  if (i + 8 <= e) {
    int s0 = ssrc[i + g];
    int s1 = ssrc[i + 4 + g];
    bf16x8 v0 = *(const bf16x8*)(hp + (size_t)s0 * HD);
    bf16x8 v1 = *(const bf16x8*)(hp + (size_t)s1 * HD);
#pragma unroll
    for (int j = 0; j < 8; ++j) acc[j] += (float)v0[j] + (float)v1[j];
    i += 8;
  }
  if (i + 4 <= e) {
    int s0 = ssrc[i + g];
    bf16x8 v0 = *(const bf16x8*)(hp + (size_t)s0 * HD);
#pragma unroll
    for (int j = 0; j < 8; ++j) acc[j] += (float)v0[j];
    i += 4;
  }
  if (i + g < e) {
    int s0 = ssrc[i + g];
    bf16x8 v0 = *(const bf16x8*)(hp + (size_t)s0 * HD);
#pragma unroll
    for (int j = 0; j < 8; ++j) acc[j] += (float)v0[j];
  }
#pragma unroll
  for (int j = 0; j < 8; ++j) {
    acc[j] += __shfl_xor(acc[j], 16);
    acc[j] += __shfl_xor(acc[j], 32);
  }
  if (g == 0) {
    float inv = (e > b) ? 1.f / (float)(e - b) : 0.f;
    bf16x8 o;
#pragma unroll
    for (int j = 0; j < 8; ++j) o[j] = (bf16_t)(acc[j] * inv);
    *(bf16x8*)(agg + (size_t)node * HD + fl * 8) = o;
  }
}

// ---- pool: block-per-graph, binary-search boundaries, writes mean (no atomics)
__global__ __launch_bounds__(256) void k_pool(const bf16_t* __restrict__ agg,
                                              const int* __restrict__ batch,
                                              float* __restrict__ p, int n) {
  __shared__ float s[256];
  int g = blockIdx.x;
  int t = threadIdx.x;
  int lo = 0, hi = n;
  while (lo < hi) { int m = (lo + hi) >> 1; if (batch[m] < g) lo = m + 1; else hi = m; }
  int lo2 = lo, hi2 = n;
  while (lo2 < hi2) { int m = (lo2 + hi2) >> 1; if (batch[m] < g + 1) lo2 = m + 1; else hi2 = m; }
  int count = lo2 - lo;
  int f = t & 127;
  int half = t >> 7;
  float acc = 0.f;
  for (int i = lo + half; i < lo2; i += 2)
    acc += (float)agg[(size_t)i * HD + f];
  s[t] = acc;
  __syncthreads();
  if (t < 128) {
    float v = s[t] + s[t + 128];
    float inv = (count > 0) ? 1.f / (float)count : 0.f;
    p[g * HD + t] = v * inv;
  }
}

// ---- head: z = p @ (w3*norm); out = mlp(z). One block per graph.
__global__ __launch_bounds__(128) void k_head(const float* __restrict__ p,
                                              const float* __restrict__ w3,
                                              const float* __restrict__ c1w, const float* __restrict__ c1b,
                                              const float* __restrict__ c2w, const float* __restrict__ c2b,
                                              const float* __restrict__ c3w, const float* __restrict__ c3b,
                                              float* __restrict__ out) {
  __shared__ float sa[128], sb[128];
  int g = blockIdx.x, t = threadIdx.x;
  sa[t] = p[g * HD + t];
  __syncthreads();
  float z = 0.f;
  for (int k = 0; k < HD; ++k) z += sa[k] * w3[k * HD + t];
  z *= TP_NORM_F;
  out[128 + g * HD + t] = z;
  sb[t] = z;
  __syncthreads();
  float o1 = c1b[t];
  for (int k = 0; k < HD; ++k) o1 += sb[k] * c1w[k * HD + t];
  o1 = fmaxf(o1, 0.f);
  __syncthreads();
  sa[t] = o1;
  __syncthreads();
  float o2 = c2b[t];
  for (int k = 0; k < HD; ++k) o2 += sa[k] * c2w[k * HD + t];
  o2 = fmaxf(o2, 0.f);
  __syncthreads();
  sb[t] = o2;
  __syncthreads();
  if (t < 2) {
    float o = c3b[t];
    for (int k = 0; k < HD; ++k) o += sb[k] * c3w[k * 2 + t];
    out[g * 2 + t] = o;
  }
}

extern "C" void kernel_launch(void* const* d_in, const int* in_sizes, int n_in,
                              void* d_out, int out_size, void* d_ws, size_t ws_size,
                              hipStream_t stream) {
  const float* x = (const float*)d_in[0];
  const int* eidx = (const int*)d_in[2];
  const int* src = eidx;
  const int* dst = eidx + N_EDGES;
  const int* batch = (const int*)d_in[3];
  const float* lin_w = (const float*)d_in[4];
  const float* lin_b = (const float*)d_in[5];
  const float* tp_w1 = (const float*)d_in[6];
  const float* tp_w2 = (const float*)d_in[7];
  const float* tp_w3 = (const float*)d_in[8];
  const float* c1w = (const float*)d_in[9];
  const float* c1b = (const float*)d_in[10];
  const float* c2w = (const float*)d_in[11];
  const float* c2b = (const float*)d_in[12];
  const float* c3w = (const float*)d_in[13];
  const float* c3b = (const float*)d_in[14];
  float* out = (float*)d_out;
  (void)in_sizes; (void)n_in; (void)out_size; (void)ws_size;

  uintptr_t wp = (uintptr_t)d_ws;
  auto alloc = [&](size_t bytes) -> void* {
    uintptr_t a = (wp + 255) & ~(uintptr_t)255;
    wp = a + bytes;
    return (void*)a;
  };
  bf16_t* WtL  = (bf16_t*)alloc(sizeof(bf16_t) * (size_t)HD * FIN);
  bf16_t* Wt1  = (bf16_t*)alloc(sizeof(bf16_t) * (size_t)HD * HD);
  bf16_t* Wt2  = (bf16_t*)alloc(sizeof(bf16_t) * (size_t)HD * HD);
  bf16_t* h    = (bf16_t*)alloc(sizeof(bf16_t) * (size_t)50048 * HD);
  bf16_t* agg  = (bf16_t*)alloc(sizeof(bf16_t) * (size_t)50048 * HD);
  int*    cnt  = (int*)alloc(sizeof(int) * N_NODES);
  int*    bsum = (int*)alloc(sizeof(int) * 256);
  int*    offs = (int*)alloc(sizeof(int) * (N_NODES + 1));
  int*    pos  = (int*)alloc(sizeof(int) * N_EDGES);
  int*    ssrc = (int*)alloc(sizeof(int) * N_EDGES);
  float*  pbuf = (float*)alloc(sizeof(float) * NG * HD);

  hipMemsetAsync(cnt, 0, sizeof(int) * N_NODES, stream);

  k_transpose_all<<<(FIN * HD + 2 * HD * HD + 255) / 256, 256, 0, stream>>>(
      lin_w, tp_w1, tp_w2, WtL, Wt1, Wt2);

  const int nScanBlocks = (N_NODES + 255) / 256;  // 196
  k_pos<<<(N_EDGES + 255) / 256, 256, 0, stream>>>(dst, cnt, pos, N_EDGES);
  k_scan1<<<nScanBlocks, 256, 0, stream>>>(cnt, bsum, N_NODES);
  k_scan2<<<1, 256, 0, stream>>>(bsum, nScanBlocks);
  k_scan3<<<nScanBlocks, 256, 0, stream>>>(cnt, bsum, offs, N_NODES);
  k_fill<<<(N_EDGES + 255) / 256, 256, 0, stream>>>(src, dst, offs, pos, ssrc, N_EDGES);

  const int gblocks = (N_NODES + 31) / 32;   // 1563
  const int ablocks = (N_NODES + 3) / 4;     // 12500

  // h0 = relu(x @ lin_w + b)
  k_gemm32<float><<<gblocks, 256, 0, stream>>>(x, WtL, lin_b, h, N_NODES, FIN, 1);

  // conv1
  k_aggregate<<<ablocks, 256, 0, stream>>>(h, ssrc, offs, agg, N_NODES);
  k_gemm32<bf16_t><<<gblocks, 256, 0, stream>>>(agg, Wt1, nullptr, h, N_NODES, HD, 1);
  // conv2
  k_aggregate<<<ablocks, 256, 0, stream>>>(h, ssrc, offs, agg, N_NODES);
  k_gemm32<bf16_t><<<gblocks, 256, 0, stream>>>(agg, Wt2, nullptr, h, N_NODES, HD, 1);
  // conv3 aggregation only (W3 folded into head)
  k_aggregate<<<ablocks, 256, 0, stream>>>(h, ssrc, offs, agg, N_NODES);

  k_pool<<<NG, 256, 0, stream>>>(agg, batch, pbuf, N_NODES);
  k_head<<<NG, 128, 0, stream>>>(pbuf, tp_w3, c1w, c1b, c2w, c2b, c3w, c3b, out);
}